// Round 8
// baseline (1646.830 us; speedup 1.0000x reference)
//
#include <hip/hip_runtime.h>
#include <hip/hip_bf16.h>
#include <stdint.h>

typedef float f32x4 __attribute__((ext_vector_type(4)));
typedef short s16x8 __attribute__((ext_vector_type(8)));
typedef unsigned short u16;

#define M_ROWS 4096
#define DIM    768
#define VOCAB  50257
#define VP2    50432           // 197 * 256 (padded vocab, 256-tile aligned)
#define KT32   1576            // VP2 / 32 global 32-vocab tiles

// ws layout (bytes) — total ~248.4 MB (< 269 MB proven-safe)
#define OFF_XB     0ull                // bf16 [4096][768]
#define OFF_WLB    6291456ull          // bf16 [768][768]
#define OFF_WVB    7471104ull          // bf16 [50432][768]
#define OFF_WVT    84934656ull         // bf16 blocked: [1576][768][32] (Wv^T tiles)
#define OFF_P      162398208ull        // bf16 [4096][<=8192] chunk P
#define OFF_ORUN   229507072ull        // f32 [4096][768]
#define OFF_LROW   242089984ull        // f32 [4096]
#define OFF_BROW   242106368ull        // f32 [4096]
#define OFF_KEYS   242122752ull        // uint[2]: {WnKey, bmaxKey}
#define OFF_H      242122880ull        // bf16 [4096][768]

__device__ __forceinline__ u16 f2bf(float f) {
    union { float f; unsigned u; } x; x.f = f;
    return (u16)((x.u + 0x7fffu + ((x.u >> 16) & 1u)) >> 16);
}
__device__ __forceinline__ float bf2f_hi(unsigned u) {
    union { unsigned u; float f; } x; x.u = u & 0xffff0000u; return x.f;
}
__device__ __forceinline__ float bf2f_lo(unsigned u) {
    union { unsigned u; float f; } x; x.u = u << 16; return x.f;
}
__device__ __forceinline__ unsigned fkey(float f) {
    union { float f; unsigned u; } x; x.f = f;
    return (x.u & 0x80000000u) ? ~x.u : (x.u | 0x80000000u);
}
__device__ __forceinline__ float fkey_dec(unsigned k) {
    union { unsigned u; float f; } x;
    x.u = (k & 0x80000000u) ? (k & 0x7fffffffu) : ~k;
    return x.f;
}
// async 16B global -> LDS; LDS dest is wave-uniform base + lane*16.
__device__ __forceinline__ void glds16(const u16* g, u16* l) {
    __builtin_amdgcn_global_load_lds(
        (const __attribute__((address_space(1))) unsigned int*)g,
        (__attribute__((address_space(3))) unsigned int*)l,
        16, 0, 0);
}

// ---------------- K0a: elementwise f32 -> bf16 cast ----------------
__global__ __launch_bounds__(256) void cast_bf16(const float* __restrict__ src,
                                                 u16* __restrict__ dst, int n4) {
    int i = blockIdx.x * 256 + threadIdx.x;
    if (i >= n4) return;
    float4 v = ((const float4*)src)[i];
    ushort4 o;
    o.x = f2bf(v.x); o.y = f2bf(v.y); o.z = f2bf(v.z); o.w = f2bf(v.w);
    ((ushort4*)dst)[i] = o;
}

// ---------------- K0b: W_vocab -> bf16 row-major, zero-padded ---------------
__global__ __launch_bounds__(256) void prep_wvb(const float* __restrict__ wv,
                                                u16* __restrict__ wvb, int ntask) {
    int t = blockIdx.x * 256 + threadIdx.x;
    if (t >= ntask) return;
    int v = t / 96, ch = t % 96;
    uint4 pk = {0u, 0u, 0u, 0u};
    if (v < VOCAB) {
        const float* p = wv + (size_t)v * DIM + ch * 8;
        float4 f0 = ((const float4*)p)[0];
        float4 f1 = ((const float4*)p)[1];
        pk.x = (unsigned)f2bf(f0.x) | ((unsigned)f2bf(f0.y) << 16);
        pk.y = (unsigned)f2bf(f0.z) | ((unsigned)f2bf(f0.w) << 16);
        pk.z = (unsigned)f2bf(f1.x) | ((unsigned)f2bf(f1.y) << 16);
        pk.w = (unsigned)f2bf(f1.z) | ((unsigned)f2bf(f1.w) << 16);
    }
    *(uint4*)(wvb + (size_t)v * DIM + ch * 8) = pk;
}

// ---------------- key init + norm/max kernels for the bound B_r -------------
__global__ void init_keys(unsigned* keys) {
    keys[0] = 0u;
    keys[1] = fkey(-3.0e38f);
}

__global__ __launch_bounds__(256) void wnorm(const u16* __restrict__ wvb,
                                             unsigned* __restrict__ keys) {
    __shared__ float part[128];
    int tid = threadIdx.x;
    int vb = blockIdx.x * 32;
    int vl = tid & 31, cg = tid >> 5;
    float s = 0.f;
    #pragma unroll
    for (int it = 0; it < 12; ++it) {
        int ch = cg + 8 * it;
        uint4 pk = *(const uint4*)(wvb + (size_t)(vb + vl) * DIM + ch * 8);
        const unsigned* pw = (const unsigned*)&pk;
        #pragma unroll
        for (int k = 0; k < 4; ++k) {
            float lo = bf2f_lo(pw[k]), hi = bf2f_hi(pw[k]);
            s += lo * lo + hi * hi;
        }
    }
    s += __shfl_xor(s, 32);
    int w = tid >> 6, lane = tid & 63;
    if (lane < 32) part[w * 32 + lane] = s;
    __syncthreads();
    if (tid < 32) {
        float t = part[tid] + part[32 + tid] + part[64 + tid] + part[96 + tid];
        float n = sqrtf(t);
        #pragma unroll
        for (int msk = 1; msk < 32; msk <<= 1) n = fmaxf(n, __shfl_xor(n, msk));
        if (tid == 0) atomicMax(&keys[0], __float_as_uint(n));
    }
}

__global__ __launch_bounds__(256) void bmax_k(const float* __restrict__ bv,
                                              unsigned* __restrict__ keys) {
    int i = blockIdx.x * 256 + threadIdx.x;
    float v = (i < VOCAB) ? bv[i] : -3.0e38f;
    #pragma unroll
    for (int msk = 1; msk < 64; msk <<= 1) v = fmaxf(v, __shfl_xor(v, msk));
    if ((threadIdx.x & 63) == 0) atomicMax(&keys[1], fkey(v));
}

__global__ __launch_bounds__(256) void xnorm(const float* __restrict__ x,
                                             const unsigned* __restrict__ keys,
                                             float* __restrict__ Brow) {
    int w = threadIdx.x >> 6, lane = threadIdx.x & 63;
    int r = blockIdx.x * 4 + w;
    const float4* p = (const float4*)(x + (size_t)r * DIM);
    float s = 0.f;
    #pragma unroll
    for (int it = 0; it < 3; ++it) {
        float4 v = p[it * 64 + lane];
        s += v.x * v.x + v.y * v.y + v.z * v.z + v.w * v.w;
    }
    #pragma unroll
    for (int msk = 1; msk < 64; msk <<= 1) s += __shfl_xor(s, msk);
    if (lane == 0) {
        float Wn = __uint_as_float(keys[0]);
        float bm = fkey_dec(keys[1]);
        Brow[r] = sqrtf(s) * Wn * 1.01f + bm + 0.1f;
    }
}

// ------- blocked Wv^T tiles: wvb [VP2][768] -> wvt32[kt][768][32] -----------
__global__ __launch_bounds__(256) void prep_wvt32(const u16* __restrict__ wvb,
                                                  u16* __restrict__ wvt32) {
    __shared__ u16 tile[32][776];
    int kt = blockIdx.x;                 // 0..KT32-1
    int vb = kt * 32;
    int tid = threadIdx.x;
    #pragma unroll
    for (int it = 0; it < 12; ++it) {
        int task = tid + 256 * it;
        int row = task / 96, ch = task % 96;
        *(uint4*)(&tile[row][ch * 8]) = *(const uint4*)(wvb + (size_t)(vb + row) * DIM + ch * 8);
    }
    __syncthreads();
    #pragma unroll
    for (int it = 0; it < 12; ++it) {
        int task = tid + 256 * it;       // 3072 tasks: d(768) x vg(4)
        int d = task >> 2, vg = task & 3;
        u16 t8[8];
        #pragma unroll
        for (int j = 0; j < 8; ++j) t8[j] = tile[vg * 8 + j][d];
        uint4 pk;
        pk.x = (unsigned)t8[0] | ((unsigned)t8[1] << 16);
        pk.y = (unsigned)t8[2] | ((unsigned)t8[3] << 16);
        pk.z = (unsigned)t8[4] | ((unsigned)t8[5] << 16);
        pk.w = (unsigned)t8[6] | ((unsigned)t8[7] << 16);
        *(uint4*)(wvt32 + (size_t)kt * 24576 + d * 32 + vg * 8) = pk;
    }
}

// ============== 256x256 BK=32 triple-buffer depth-2 K-loop ==================
// 1024 threads / 16 waves (4M x 4N), per-wave C = 64x64 (acc[4][4] = 64 VGPR).
// LDS: 3 bufs x (A[256][32] 16KB | B[256][32] 16KB) = 96 KB.
// Per K-step: stage tile t+2 (2 glds16/thread), ds_read 8 frags from tile t,
// 16 MFMA, then ONE vmcnt(2) (drains t+1's pair, keeps t+2's pair in flight
// across the barrier - T4 counted-vmcnt, minimal form) + ONE s_barrier.
// Ledger: tile t staged at iter t-2; drained by vmcnt(2) at end of iter t-1
// (outstanding there: t's pair older + t+1's pair newer = 4 -> wait<=2 drains
// t's). WAR: stage target p2 at iter t = buffer read at iter t-1; those reads
// are lgkm-complete before iter t-1's MFMAs/barrier. Exit: vmcnt(0) drain so
// clamped garbage stages land before LDS reuse / endpgm.
// Swizzle (both-sides): LDS[row][q] holds global[row][q ^ (row&3)]; read at
// q' = q ^ (c&3) (row%4 == c%4) -> lane gets global chunk q. 4-way residual
// read conflict (64B rows), hidden under MFMA.
__device__ __forceinline__ void kloop2(char* LDS,
                                       const u16* __restrict__ gA, size_t sA,
                                       const u16* __restrict__ gB, size_t sB,
                                       int nk, int tid, f32x4 (&acc)[4][4]) {
    const int lane = tid & 63, w = tid >> 6;
    const int c = lane & 15, q = (lane >> 4) & 3;
    const int wm = w & 3, wn = w >> 2;
    const int xsw = (q ^ (c & 3)) * 16;
    char* p0 = LDS;
    char* p1 = LDS + 32768;
    char* p2 = LDS + 65536;

    glds16(gA, (u16*)(p0 + (size_t)tid * 16));
    glds16(gB, (u16*)(p0 + 16384 + (size_t)tid * 16));
    {
        size_t t1 = (nk > 1) ? 1 : 0;
        glds16(gA + t1 * sA, (u16*)(p1 + (size_t)tid * 16));
        glds16(gB + t1 * sB, (u16*)(p1 + 16384 + (size_t)tid * 16));
    }
    asm volatile("s_waitcnt vmcnt(2)" ::: "memory");
    __builtin_amdgcn_sched_barrier(0);
    __builtin_amdgcn_s_barrier();
    __builtin_amdgcn_sched_barrier(0);

    #pragma unroll 1
    for (int t = 0; t < nk; ++t) {
        size_t t2 = (size_t)((t + 2 < nk) ? (t + 2) : (nk - 1));
        glds16(gA + t2 * sA, (u16*)(p2 + (size_t)tid * 16));
        glds16(gB + t2 * sB, (u16*)(p2 + 16384 + (size_t)tid * 16));
        s16x8 af[4], bf[4];
        #pragma unroll
        for (int i = 0; i < 4; ++i)
            af[i] = *(const s16x8*)(p0 + (wm * 64 + i * 16 + c) * 64 + xsw);
        #pragma unroll
        for (int j = 0; j < 4; ++j)
            bf[j] = *(const s16x8*)(p0 + 16384 + (wn * 64 + j * 16 + c) * 64 + xsw);
        #pragma unroll
        for (int i = 0; i < 4; ++i)
            #pragma unroll
            for (int j = 0; j < 4; ++j)
                acc[i][j] = __builtin_amdgcn_mfma_f32_16x16x32_bf16(af[i], bf[j], acc[i][j], 0, 0, 0);
        asm volatile("s_waitcnt vmcnt(2)" ::: "memory");
        __builtin_amdgcn_sched_barrier(0);
        __builtin_amdgcn_s_barrier();
        __builtin_amdgcn_sched_barrier(0);
        char* tp = p0; p0 = p1; p1 = p2; p2 = tp;
    }
    asm volatile("s_waitcnt vmcnt(0)" ::: "memory");
    __builtin_amdgcn_sched_barrier(0);
    __builtin_amdgcn_s_barrier();
}

// -------- GEMM1: P = exp(z - B_row) bf16; row-sums atomically into Lrow -----
__global__ __launch_bounds__(1024, 4) void gemm1(
    const u16* __restrict__ xb, const u16* __restrict__ wvb,
    const float* __restrict__ bvocab, const float* __restrict__ Brow,
    u16* __restrict__ P, float* __restrict__ Lrow, int v0, int CN) {
    __shared__ __align__(16) char LDS[98304];
    __shared__ float BL[256];
    int tid = threadIdx.x;
    int nwg = gridDim.x, cpx = nwg >> 3;
    int bid = blockIdx.x;
    bid = (bid & 7) * cpx + (bid >> 3);            // XCD-chunked (nwg%8==0)
    int mt = bid & 15, nt = bid >> 4;              // consecutive bids share nt (B panel)
    if (tid < 256) BL[tid] = Brow[mt * 256 + tid];
    f32x4 acc[4][4];
    #pragma unroll
    for (int i = 0; i < 4; ++i)
        #pragma unroll
        for (int j = 0; j < 4; ++j) acc[i][j] = (f32x4){0.f, 0.f, 0.f, 0.f};

    int row = tid >> 2;
    int qg = (tid & 3) ^ (row & 3);
    const u16* gA = xb + (size_t)(mt * 256 + row) * DIM + qg * 8;
    const u16* gB = wvb + (size_t)(v0 + nt * 256 + row) * DIM + qg * 8;
    kloop2(LDS, gA, 32, gB, 32, 24, tid, acc);

    int lane = tid & 63, w = tid >> 6, c = lane & 15, q = (lane >> 4) & 3;
    int wm = w & 3, wn = w >> 2;
    float bvv[4]; bool vok[4];
    #pragma unroll
    for (int n = 0; n < 4; ++n) {
        int vg = v0 + nt * 256 + wn * 64 + n * 16 + c;
        vok[n] = vg < VOCAB;
        bvv[n] = vok[n] ? bvocab[vg] : 0.f;
    }
    #pragma unroll
    for (int i = 0; i < 4; ++i)
        #pragma unroll
        for (int jr = 0; jr < 4; ++jr) {
            int rloc = wm * 64 + i * 16 + q * 4 + jr;
            float B = BL[rloc];
            float s = 0.f;
            #pragma unroll
            for (int n = 0; n < 4; ++n) {
                float z = acc[i][n][jr] + bvv[n];
                float e = vok[n] ? __expf(z - B) : 0.f;
                acc[i][n][jr] = e;
                s += e;
            }
            s += __shfl_xor(s, 1); s += __shfl_xor(s, 2);
            s += __shfl_xor(s, 4); s += __shfl_xor(s, 8);
            if (c == 0) atomicAdd(&Lrow[mt * 256 + rloc], s);
        }
    // P write via two half-tile LDS bounces ([128][256] u16 = 64 KiB)
    u16* Pt = (u16*)LDS;
    #pragma unroll
    for (int h = 0; h < 2; ++h) {
        if (h) __syncthreads();
        if ((wm >> 1) == h) {
            #pragma unroll
            for (int i = 0; i < 4; ++i)
                #pragma unroll
                for (int jr = 0; jr < 4; ++jr) {
                    int r = (wm & 1) * 64 + i * 16 + q * 4 + jr;
                    #pragma unroll
                    for (int n = 0; n < 4; ++n)
                        Pt[r * 256 + wn * 64 + n * 16 + c] = f2bf(acc[i][n][jr]);
                }
        }
        __syncthreads();
        #pragma unroll
        for (int itc = 0; itc < 4; ++itc) {
            int task = tid + itc * 1024;
            int r = task >> 5, chn = task & 31;
            uint4 pk = *(const uint4*)(Pt + r * 256 + chn * 8);
            *(uint4*)(P + (size_t)(mt * 256 + h * 128 + r) * CN + nt * 256 + chn * 8) = pk;
        }
    }
}

// -------- GEMM2: Orun += P @ Wv  (256x256, 6-way split-K atomic) ------------
__global__ __launch_bounds__(1024, 4) void gemm2(
    const u16* __restrict__ P, const u16* __restrict__ wvt32,
    float* __restrict__ Orun, int CN, int v0, int KT) {
    __shared__ __align__(16) char LDS[98304];
    int tid = threadIdx.x;
    int bid = (blockIdx.x & 7) * 36 + (blockIdx.x >> 3);   // grid 288, cpx 36
    int s = bid / 48;
    int rem = bid % 48;
    int nd = rem >> 4, mt = rem & 15;                      // consecutive share (s,nd) B
    int ks0 = (KT + 5) / 6;
    int k0 = s * ks0;
    if (k0 >= KT) return;
    int nk = (k0 + ks0 <= KT) ? ks0 : (KT - k0);
    f32x4 acc[4][4];
    #pragma unroll
    for (int i = 0; i < 4; ++i)
        #pragma unroll
        for (int j = 0; j < 4; ++j) acc[i][j] = (f32x4){0.f, 0.f, 0.f, 0.f};

    int row = tid >> 2;
    int qg = (tid & 3) ^ (row & 3);
    const u16* gA = P + (size_t)(mt * 256 + row) * CN + (size_t)k0 * 32 + qg * 8;
    const u16* gB = wvt32 + (size_t)((v0 >> 5) + k0) * 24576 + (size_t)(nd * 256 + row) * 32 + qg * 8;
    kloop2(LDS, gA, 32, gB, 24576, nk, tid, acc);

    int lane = tid & 63, w = tid >> 6, c = lane & 15, q = (lane >> 4) & 3;
    int wm = w & 3, wn = w >> 2;
    #pragma unroll
    for (int i = 0; i < 4; ++i)
        #pragma unroll
        for (int n = 0; n < 4; ++n) {
            int col = nd * 256 + wn * 64 + n * 16 + c;
            #pragma unroll
            for (int jr = 0; jr < 4; ++jr) {
                int rg = mt * 256 + wm * 64 + i * 16 + q * 4 + jr;
                atomicAdd(&Orun[(size_t)rg * DIM + col], acc[i][n][jr]);
            }
        }
}

__global__ __launch_bounds__(256) void final_h(const float* __restrict__ Orun,
                                               const float* __restrict__ Lrow,
                                               u16* __restrict__ h) {
    int idx = blockIdx.x * 256 + threadIdx.x;
    if (idx >= M_ROWS * DIM) return;
    int r = idx / DIM;
    h[idx] = f2bf(Orun[idx] / Lrow[r]);
}

// ---------------- K3: out = h @ W_lin^T + b_lin (128-tile m97 style) --------
__global__ __launch_bounds__(256, 2) void final_gemm(const u16* __restrict__ h,
                                                     const u16* __restrict__ wlb,
                                                     const float* __restrict__ blin,
                                                     float* __restrict__ out) {
    __shared__ u16 At[4096];
    __shared__ u16 Bt[4096];
    int mb = blockIdx.x & 31, eb = blockIdx.x >> 5;
    int tid = threadIdx.x;
    int w = tid >> 6, lane = tid & 63, q = lane >> 4, c = lane & 15;
    int wm = w & 1, wn = w >> 1;
    int trow = tid >> 2, tch = tid & 3;
    const u16* gA0 = h + (size_t)(mb * 128 + trow) * DIM + tch * 8;
    const u16* gA1 = h + (size_t)(mb * 128 + 64 + trow) * DIM + tch * 8;
    const u16* gB0 = wlb + (size_t)(eb * 128 + trow) * DIM + tch * 8;
    const u16* gB1 = wlb + (size_t)(eb * 128 + 64 + trow) * DIM + tch * 8;
    f32x4 acc[4][4];
    #pragma unroll
    for (int i = 0; i < 4; ++i)
        #pragma unroll
        for (int j = 0; j < 4; ++j) acc[i][j] = (f32x4){0.f, 0.f, 0.f, 0.f};

    for (int ko = 0; ko < 24; ++ko) {
        glds16(gA0 + ko * 32, At + tid * 8);
        glds16(gA1 + ko * 32, At + (tid + 256) * 8);
        glds16(gB0 + ko * 32, Bt + tid * 8);
        glds16(gB1 + ko * 32, Bt + (tid + 256) * 8);
        __syncthreads();
        s16x8 af[4], bf[4];
        #pragma unroll
        for (int i = 0; i < 4; ++i)
            af[i] = *(const s16x8*)(At + (wm * 64 + i * 16 + c) * 32 + q * 8);
        #pragma unroll
        for (int j = 0; j < 4; ++j)
            bf[j] = *(const s16x8*)(Bt + (wn * 64 + j * 16 + c) * 32 + q * 8);
        #pragma unroll
        for (int i = 0; i < 4; ++i)
            #pragma unroll
            for (int j = 0; j < 4; ++j)
                acc[i][j] = __builtin_amdgcn_mfma_f32_16x16x32_bf16(af[i], bf[j], acc[i][j], 0, 0, 0);
        __syncthreads();
    }
    #pragma unroll
    for (int j = 0; j < 4; ++j) {
        int e = eb * 128 + wn * 64 + j * 16 + c;
        float bl = blin[e];
        #pragma unroll
        for (int i = 0; i < 4; ++i) {
            #pragma unroll
            for (int jr = 0; jr < 4; ++jr) {
                int rg = mb * 128 + wm * 64 + i * 16 + q * 4 + jr;
                out[(size_t)rg * DIM + e] = acc[i][j][jr] + bl;
            }
        }
    }
}

extern "C" void kernel_launch(void* const* d_in, const int* in_sizes, int n_in,
                              void* d_out, int out_size, void* d_ws, size_t ws_size,
                              hipStream_t stream) {
    const float* x  = (const float*)d_in[0];
    const float* Wv = (const float*)d_in[1];
    const float* bv = (const float*)d_in[2];
    const float* Wl = (const float*)d_in[3];
    const float* bl = (const float*)d_in[4];
    float* out = (float*)d_out;
    char* ws = (char*)d_ws;

    u16* xb    = (u16*)(ws + OFF_XB);
    u16* wlb   = (u16*)(ws + OFF_WLB);
    u16* wvb   = (u16*)(ws + OFF_WVB);
    u16* wvt32 = (u16*)(ws + OFF_WVT);
    u16* P     = (u16*)(ws + OFF_P);
    float* Orun  = (float*)(ws + OFF_ORUN);
    float* Lrow  = (float*)(ws + OFF_LROW);
    float* Brow  = (float*)(ws + OFF_BROW);
    unsigned* keys = (unsigned*)(ws + OFF_KEYS);
    u16* h       = (u16*)(ws + OFF_H);

    cast_bf16<<<(M_ROWS * DIM / 4 + 255) / 256, 256, 0, stream>>>(x, xb, M_ROWS * DIM / 4);
    cast_bf16<<<(DIM * DIM / 4 + 255) / 256, 256, 0, stream>>>(Wl, wlb, DIM * DIM / 4);
    {
        int ntask = VP2 * 96;
        prep_wvb<<<(ntask + 255) / 256, 256, 0, stream>>>(Wv, wvb, ntask);
    }
    init_keys<<<1, 1, 0, stream>>>(keys);
    hipMemsetAsync(Orun, 0, (size_t)M_ROWS * DIM * 4, stream);
    hipMemsetAsync(Lrow, 0, (size_t)M_ROWS * 4, stream);
    wnorm<<<VP2 / 32, 256, 0, stream>>>(wvb, keys);
    bmax_k<<<(VOCAB + 255) / 256, 256, 0, stream>>>(bv, keys);
    xnorm<<<M_ROWS / 4, 256, 0, stream>>>(x, keys, Brow);
    prep_wvt32<<<KT32, 256, 0, stream>>>(wvb, wvt32);

    // 7 chunks in 256-col tiles: 6x32 + 5 (197 tiles = 50432 cols)
    static const int chunk_start[7] = {0, 32, 64, 96, 128, 160, 192};
    static const int chunk_cnt[7]   = {32, 32, 32, 32, 32, 32, 5};
    for (int ci = 0; ci < 7; ++ci) {
        int cnt = chunk_cnt[ci];
        int v0 = chunk_start[ci] * 256;
        int CN = cnt * 256;
        int KT = CN / 32;                 // 32-vocab K-steps in this chunk
        gemm1<<<16 * cnt, 1024, 0, stream>>>(xb, wvb, bv, Brow, P, Lrow, v0, CN);
        gemm2<<<288, 1024, 0, stream>>>(P, wvt32, Orun, CN, v0, KT);
    }
    final_h<<<(M_ROWS * DIM + 255) / 256, 256, 0, stream>>>(Orun, Lrow, h);
    final_gemm<<<192, 256, 0, stream>>>(h, wlb, bl, out);
}

// Round 10
// 1362.537 us; speedup vs baseline: 1.2086x; 1.2086x over previous
//
#include <hip/hip_runtime.h>
#include <hip/hip_bf16.h>
#include <stdint.h>

typedef float f32x4 __attribute__((ext_vector_type(4)));
typedef short s16x8 __attribute__((ext_vector_type(8)));
typedef unsigned short u16;

#define M_ROWS 4096
#define DIM    768
#define VOCAB  50257
#define VP2    50432           // 197 * 256 (padded vocab, 256-tile aligned)
#define KT32   1576            // VP2 / 32 global 32-vocab tiles

// ws layout (bytes) — total ~265.2 MB (< 269 MB proven-safe)
#define OFF_XB     0ull                // bf16 [4096][768]
#define OFF_WLB    6291456ull          // bf16 [768][768]
#define OFF_WVB    7471104ull          // bf16 [50432][768]
#define OFF_WVT    84934656ull         // bf16 blocked: [1576][768][32] (Wv^T tiles)
#define OFF_P      162398208ull        // bf16 [4096][<=10240] chunk P
#define OFF_ORUN   246284288ull        // f32 [4096][768]
#define OFF_LROW   258867200ull        // f32 [4096]
#define OFF_BROW   258883584ull        // f32 [4096]
#define OFF_KEYS   258899968ull        // uint[2]: {WnKey, bmaxKey}
#define OFF_H      258900096ull        // bf16 [4096][768]

__device__ __forceinline__ u16 f2bf(float f) {
    union { float f; unsigned u; } x; x.f = f;
    return (u16)((x.u + 0x7fffu + ((x.u >> 16) & 1u)) >> 16);
}
__device__ __forceinline__ float bf2f_hi(unsigned u) {
    union { unsigned u; float f; } x; x.u = u & 0xffff0000u; return x.f;
}
__device__ __forceinline__ float bf2f_lo(unsigned u) {
    union { unsigned u; float f; } x; x.u = u << 16; return x.f;
}
__device__ __forceinline__ unsigned fkey(float f) {
    union { float f; unsigned u; } x; x.f = f;
    return (x.u & 0x80000000u) ? ~x.u : (x.u | 0x80000000u);
}
__device__ __forceinline__ float fkey_dec(unsigned k) {
    union { unsigned u; float f; } x;
    x.u = (k & 0x80000000u) ? (k & 0x7fffffffu) : ~k;
    return x.f;
}
// async 16B global -> LDS; LDS dest is wave-uniform base + lane*16.
__device__ __forceinline__ void glds16(const u16* g, u16* l) {
    __builtin_amdgcn_global_load_lds(
        (const __attribute__((address_space(1))) unsigned int*)g,
        (__attribute__((address_space(3))) unsigned int*)l,
        16, 0, 0);
}

// ---------------- K0a: elementwise f32 -> bf16 cast ----------------
__global__ __launch_bounds__(256) void cast_bf16(const float* __restrict__ src,
                                                 u16* __restrict__ dst, int n4) {
    int i = blockIdx.x * 256 + threadIdx.x;
    if (i >= n4) return;
    float4 v = ((const float4*)src)[i];
    ushort4 o;
    o.x = f2bf(v.x); o.y = f2bf(v.y); o.z = f2bf(v.z); o.w = f2bf(v.w);
    ((ushort4*)dst)[i] = o;
}

// ---------------- K0b: W_vocab -> bf16 row-major, zero-padded ---------------
__global__ __launch_bounds__(256) void prep_wvb(const float* __restrict__ wv,
                                                u16* __restrict__ wvb, int ntask) {
    int t = blockIdx.x * 256 + threadIdx.x;
    if (t >= ntask) return;
    int v = t / 96, ch = t % 96;
    uint4 pk = {0u, 0u, 0u, 0u};
    if (v < VOCAB) {
        const float* p = wv + (size_t)v * DIM + ch * 8;
        float4 f0 = ((const float4*)p)[0];
        float4 f1 = ((const float4*)p)[1];
        pk.x = (unsigned)f2bf(f0.x) | ((unsigned)f2bf(f0.y) << 16);
        pk.y = (unsigned)f2bf(f0.z) | ((unsigned)f2bf(f0.w) << 16);
        pk.z = (unsigned)f2bf(f1.x) | ((unsigned)f2bf(f1.y) << 16);
        pk.w = (unsigned)f2bf(f1.z) | ((unsigned)f2bf(f1.w) << 16);
    }
    *(uint4*)(wvb + (size_t)v * DIM + ch * 8) = pk;
}

// ---------------- key init + norm/max kernels for the bound B_r -------------
__global__ void init_keys(unsigned* keys) {
    keys[0] = 0u;
    keys[1] = fkey(-3.0e38f);
}

__global__ __launch_bounds__(256) void wnorm(const u16* __restrict__ wvb,
                                             unsigned* __restrict__ keys) {
    __shared__ float part[128];
    int tid = threadIdx.x;
    int vb = blockIdx.x * 32;
    int vl = tid & 31, cg = tid >> 5;
    float s = 0.f;
    #pragma unroll
    for (int it = 0; it < 12; ++it) {
        int ch = cg + 8 * it;
        uint4 pk = *(const uint4*)(wvb + (size_t)(vb + vl) * DIM + ch * 8);
        const unsigned* pw = (const unsigned*)&pk;
        #pragma unroll
        for (int k = 0; k < 4; ++k) {
            float lo = bf2f_lo(pw[k]), hi = bf2f_hi(pw[k]);
            s += lo * lo + hi * hi;
        }
    }
    s += __shfl_xor(s, 32);
    int w = tid >> 6, lane = tid & 63;
    if (lane < 32) part[w * 32 + lane] = s;
    __syncthreads();
    if (tid < 32) {
        float t = part[tid] + part[32 + tid] + part[64 + tid] + part[96 + tid];
        float n = sqrtf(t);
        #pragma unroll
        for (int msk = 1; msk < 32; msk <<= 1) n = fmaxf(n, __shfl_xor(n, msk));
        if (tid == 0) atomicMax(&keys[0], __float_as_uint(n));
    }
}

__global__ __launch_bounds__(256) void bmax_k(const float* __restrict__ bv,
                                              unsigned* __restrict__ keys) {
    int i = blockIdx.x * 256 + threadIdx.x;
    float v = (i < VOCAB) ? bv[i] : -3.0e38f;
    #pragma unroll
    for (int msk = 1; msk < 64; msk <<= 1) v = fmaxf(v, __shfl_xor(v, msk));
    if ((threadIdx.x & 63) == 0) atomicMax(&keys[1], fkey(v));
}

__global__ __launch_bounds__(256) void xnorm(const float* __restrict__ x,
                                             const unsigned* __restrict__ keys,
                                             float* __restrict__ Brow) {
    int w = threadIdx.x >> 6, lane = threadIdx.x & 63;
    int r = blockIdx.x * 4 + w;
    const float4* p = (const float4*)(x + (size_t)r * DIM);
    float s = 0.f;
    #pragma unroll
    for (int it = 0; it < 3; ++it) {
        float4 v = p[it * 64 + lane];
        s += v.x * v.x + v.y * v.y + v.z * v.z + v.w * v.w;
    }
    #pragma unroll
    for (int msk = 1; msk < 64; msk <<= 1) s += __shfl_xor(s, msk);
    if (lane == 0) {
        float Wn = __uint_as_float(keys[0]);
        float bm = fkey_dec(keys[1]);
        Brow[r] = sqrtf(s) * Wn * 1.01f + bm + 0.1f;
    }
}

// ------- blocked Wv^T tiles: wvb [VP2][768] -> wvt32[kt][768][32] -----------
__global__ __launch_bounds__(256) void prep_wvt32(const u16* __restrict__ wvb,
                                                  u16* __restrict__ wvt32) {
    __shared__ u16 tile[32][776];
    int kt = blockIdx.x;                 // 0..KT32-1
    int vb = kt * 32;
    int tid = threadIdx.x;
    #pragma unroll
    for (int it = 0; it < 12; ++it) {
        int task = tid + 256 * it;
        int row = task / 96, ch = task % 96;
        *(uint4*)(&tile[row][ch * 8]) = *(const uint4*)(wvb + (size_t)(vb + row) * DIM + ch * 8);
    }
    __syncthreads();
    #pragma unroll
    for (int it = 0; it < 12; ++it) {
        int task = tid + 256 * it;       // 3072 tasks: d(768) x vg(4)
        int d = task >> 2, vg = task & 3;
        u16 t8[8];
        #pragma unroll
        for (int j = 0; j < 8; ++j) t8[j] = tile[vg * 8 + j][d];
        uint4 pk;
        pk.x = (unsigned)t8[0] | ((unsigned)t8[1] << 16);
        pk.y = (unsigned)t8[2] | ((unsigned)t8[3] << 16);
        pk.z = (unsigned)t8[4] | ((unsigned)t8[5] << 16);
        pk.w = (unsigned)t8[6] | ((unsigned)t8[7] << 16);
        *(uint4*)(wvt32 + (size_t)kt * 24576 + d * 32 + vg * 8) = pk;
    }
}

// ====================== 256x256 4-window K-loop (gemm1, R4-proven) ==========
template<int MH, int NH>
__device__ __forceinline__ void mfma_quad(f32x4 (&acc)[8][4],
                                          const s16x8 (&afr)[4][2],
                                          const s16x8 (&bfr)[2][2][2]) {
    #pragma unroll
    for (int mi = 0; mi < 4; ++mi)
        #pragma unroll
        for (int ni = 0; ni < 2; ++ni) {
            f32x4 a_ = acc[MH * 4 + mi][NH * 2 + ni];
            a_ = __builtin_amdgcn_mfma_f32_16x16x32_bf16(afr[mi][0], bfr[NH][ni][0], a_, 0, 0, 0);
            a_ = __builtin_amdgcn_mfma_f32_16x16x32_bf16(afr[mi][1], bfr[NH][ni][1], a_, 0, 0, 0);
            acc[MH * 4 + mi][NH * 2 + ni] = a_;
        }
}

#define STG(g, pitch, rowbase, kcol, ldst) do {                                   \
    const u16* _s0 = (g) + (size_t)((rowbase) + rlo) * (pitch) + (kcol) + offu;   \
    const u16* _s1 = _s0 + (size_t)64 * (pitch);                                  \
    glds16(_s0, (u16*)(ldst) + (size_t)tid * 8);                                  \
    glds16(_s1, (u16*)(ldst) + (size_t)tid * 8 + 4096);                           \
} while (0)

#define RD_A(buf, mh) do { _Pragma("unroll")                                              \
    for (int _mi = 0; _mi < 4; ++_mi) {                                                   \
        afr[_mi][0] = *(const s16x8*)((buf) + ((abase + ((mh)*4 + _mi)*2048)      ^ asw));\
        afr[_mi][1] = *(const s16x8*)((buf) + ((abase + ((mh)*4 + _mi)*2048 + 64) ^ asw));\
    } } while (0)

#define RD_B(buf, nh) do { _Pragma("unroll")                                              \
    for (int _ni = 0; _ni < 2; ++_ni) {                                                   \
        bfr[nh][_ni][0] = *(const s16x8*)((buf) + ((bbase + ((nh)*2 + _ni)*2048)      ^ asw));\
        bfr[nh][_ni][1] = *(const s16x8*)((buf) + ((bbase + ((nh)*2 + _ni)*2048 + 64) ^ asw));\
    } } while (0)

#define SP1() __builtin_amdgcn_s_setprio(1)
#define SP0() __builtin_amdgcn_s_setprio(0)
#define BARRIER() __builtin_amdgcn_s_barrier()
#define WAIT_VM4() do { asm volatile("s_waitcnt vmcnt(4)" ::: "memory"); \
    __builtin_amdgcn_sched_barrier(0); } while (0)
#define WAIT_LGKM0() do { asm volatile("s_waitcnt lgkmcnt(0)" ::: "memory"); \
    __builtin_amdgcn_sched_barrier(0); } while (0)

__device__ __forceinline__ void kloop256(char* LDS,
                                         const u16* __restrict__ gA, int pA,
                                         const u16* __restrict__ gB, int pB, int ksB,
                                         int NT, int tid, f32x4 (&acc)[8][4]) {
    const int lane = tid & 63, w = tid >> 6;
    const int c = lane & 15, q = (lane >> 4) & 3;
    const int wm = w & 1, wn = w >> 1;
    const int asw = (c & 7) << 4;
    const int abase = wm * 16384 + c * 128 + q * 16;
    const int bbase = (wn >> 1) * 16384 + (wn & 1) * 8192 + c * 128 + q * 16;
    const int rlo = tid >> 3;
    const int offu = ((tid & 7) * 8) ^ ((rlo & 7) << 3);
    char* A0 = LDS;
    char* B0 = LDS + 32768;
    char* A1 = LDS + 65536;
    char* B1 = LDS + 98304;
    s16x8 afr[4][2], bfr[2][2][2];
    const int ktN = NT - 1;

    STG(gA, pA, 0,   0, A0);
    STG(gA, pA, 128, 0, A0 + 16384);
    STG(gB, pB, 0,   0, B0);
    STG(gB, pB, 128, 0, B0 + 16384);
    {
        int t1 = (1 <= ktN) ? 1 : ktN;
        STG(gB, pB, 0,   t1 * ksB, B1);
        STG(gB, pB, 128, t1 * ksB, B1 + 16384);
    }
    WAIT_VM4();
    BARRIER();

    const int nit = NT >> 1;
    #pragma unroll 1
    for (int it2 = 0; it2 < nit; ++it2) {
        int t1 = (2 * it2 + 1 <= ktN) ? 2 * it2 + 1 : ktN;
        int t2 = (2 * it2 + 2 <= ktN) ? 2 * it2 + 2 : ktN;
        int t3 = (2 * it2 + 3 <= ktN) ? 2 * it2 + 3 : ktN;
        // ---- W0 ----
        RD_A(A0, 0); RD_B(B0, 0); RD_B(B0, 1);
        STG(gA, pA, 0,   t1 * 64, A1);
        STG(gA, pA, 128, t1 * 64, A1 + 16384);
        SP1(); mfma_quad<0, 0>(acc, afr, bfr); SP0();
        WAIT_LGKM0();
        BARRIER();
        // ---- W1 ----
        STG(gB, pB, 0,   t2 * ksB, B0);
        STG(gB, pB, 128, t2 * ksB, B0 + 16384);
        SP1(); mfma_quad<0, 1>(acc, afr, bfr); SP0();
        RD_A(A0, 1);
        SP1(); mfma_quad<1, 0>(acc, afr, bfr);
               mfma_quad<1, 1>(acc, afr, bfr); SP0();
        WAIT_VM4();
        BARRIER();
        // ---- W2 ----
        RD_A(A1, 0); RD_B(B1, 0); RD_B(B1, 1);
        STG(gA, pA, 0,   t2 * 64, A0);
        STG(gA, pA, 128, t2 * 64, A0 + 16384);
        SP1(); mfma_quad<0, 0>(acc, afr, bfr); SP0();
        WAIT_LGKM0();
        BARRIER();
        // ---- W3 ----
        STG(gB, pB, 0,   t3 * ksB, B1);
        STG(gB, pB, 128, t3 * ksB, B1 + 16384);
        SP1(); mfma_quad<0, 1>(acc, afr, bfr); SP0();
        RD_A(A1, 1);
        SP1(); mfma_quad<1, 0>(acc, afr, bfr);
               mfma_quad<1, 1>(acc, afr, bfr); SP0();
        WAIT_VM4();
        BARRIER();
    }
    // in flight at exit: <=4 load-instrs targeting B1 (upper LDS) only.
}

// -------- GEMM1: P = exp(z - B_row) bf16; row-sums atomically into Lrow -----
__global__ __launch_bounds__(512, 2) void gemm1(
    const u16* __restrict__ xb, const u16* __restrict__ wvb,
    const float* __restrict__ bvocab, const float* __restrict__ Brow,
    u16* __restrict__ P, float* __restrict__ Lrow, int v0, int CN) {
    __shared__ __align__(16) char LDS[131072];
    __shared__ float BL[256];
    int tid = threadIdx.x;
    int nwg = gridDim.x, cpx = nwg >> 3;
    int bid = blockIdx.x;
    bid = (bid & 7) * cpx + (bid >> 3);            // XCD-chunked (nwg%8==0)
    int mt = bid & 15, nt = bid >> 4;
    if (tid < 256) BL[tid] = Brow[mt * 256 + tid];
    f32x4 acc[8][4];
    #pragma unroll
    for (int i = 0; i < 8; ++i)
        #pragma unroll
        for (int j = 0; j < 4; ++j) acc[i][j] = (f32x4){0.f, 0.f, 0.f, 0.f};
    kloop256(LDS, xb + (size_t)(mt * 256) * DIM, DIM,
             wvb + (size_t)(v0 + nt * 256) * DIM, DIM, 64, 12, tid, acc);

    int lane = tid & 63, w = tid >> 6, c = lane & 15, q = (lane >> 4) & 3;
    int wm = w & 1, wn = w >> 1;
    float bvv[4]; bool vok[4];
    #pragma unroll
    for (int n = 0; n < 4; ++n) {
        int vg = v0 + nt * 256 + wn * 64 + n * 16 + c;
        vok[n] = vg < VOCAB;
        bvv[n] = vok[n] ? bvocab[vg] : 0.f;
    }
    #pragma unroll
    for (int m = 0; m < 8; ++m)
        #pragma unroll
        for (int jr = 0; jr < 4; ++jr) {
            int rloc = wm * 128 + m * 16 + q * 4 + jr;
            float B = BL[rloc];
            float s = 0.f;
            #pragma unroll
            for (int n = 0; n < 4; ++n) {
                float z = acc[m][n][jr] + bvv[n];
                float e = vok[n] ? __expf(z - B) : 0.f;
                acc[m][n][jr] = e;
                s += e;
            }
            s += __shfl_xor(s, 1); s += __shfl_xor(s, 2);
            s += __shfl_xor(s, 4); s += __shfl_xor(s, 8);
            if (c == 0) atomicAdd(&Lrow[mt * 256 + rloc], s);
        }
    // P write via two half-tile LDS bounces ([128][256] u16 = 64 KiB, lower LDS)
    u16* Pt = (u16*)LDS;
    #pragma unroll
    for (int h = 0; h < 2; ++h) {
        if (h) __syncthreads();
        if (wm == h) {
            #pragma unroll
            for (int m = 0; m < 8; ++m)
                #pragma unroll
                for (int jr = 0; jr < 4; ++jr) {
                    int r = m * 16 + q * 4 + jr;
                    #pragma unroll
                    for (int n = 0; n < 4; ++n)
                        Pt[r * 256 + wn * 64 + n * 16 + c] = f2bf(acc[m][n][jr]);
                }
        }
        __syncthreads();
        #pragma unroll
        for (int itc = 0; itc < 8; ++itc) {
            int task = tid + itc * 512;
            int r = task >> 5, chn = task & 31;
            uint4 pk = *(const uint4*)(Pt + r * 256 + chn * 8);
            *(uint4*)(P + (size_t)(mt * 256 + h * 128 + r) * CN + nt * 256 + chn * 8) = pk;
        }
    }
}

// -------- GEMM2: Orun += P @ Wv_chunk (128² m97 2-barrier, R0-proven) -------
// 4-way split-K atomic; B from global blocked wvt32 tiles [kt][768][32].
__global__ __launch_bounds__(256, 2) void gemm2(
    const u16* __restrict__ P, const u16* __restrict__ wvt32,
    float* __restrict__ Orun, int CN, int v0, int kt32_total, int kts) {
    __shared__ u16 At[4096];
    __shared__ u16 Bt[4096];
    int bid = blockIdx.x;
    bid = (bid & 7) * 96 + (bid >> 3);             // grid 768, cpx 96
    int mb = bid & 31;
    int rest = bid >> 5;
    int nb = rest % 6, s = rest / 6;
    int kt0 = s * kts;
    int kt1 = kt0 + kts; if (kt1 > kt32_total) kt1 = kt32_total;
    int tid = threadIdx.x;
    int w = tid >> 6, lane = tid & 63, q = lane >> 4, c = lane & 15;
    int wm = w & 1, wn = w >> 1;
    int trow = tid >> 2, tch = tid & 3;
    const u16* gA0 = P + (size_t)(mb * 128 + trow) * CN + tch * 8;
    const u16* gA1 = P + (size_t)(mb * 128 + 64 + trow) * CN + tch * 8;
    const u16* wvtb = wvt32 + (size_t)(v0 >> 5) * 24576;
    const u16* gB0 = wvtb + (size_t)(nb * 128 + trow) * 32 + tch * 8;
    const u16* gB1 = wvtb + (size_t)(nb * 128 + 64 + trow) * 32 + tch * 8;
    f32x4 acc[4][4];
    #pragma unroll
    for (int i = 0; i < 4; ++i)
        #pragma unroll
        for (int j = 0; j < 4; ++j) acc[i][j] = (f32x4){0.f, 0.f, 0.f, 0.f};

    for (int kt = kt0; kt < kt1; ++kt) {
        glds16(gA0 + kt * 32, At + tid * 8);
        glds16(gA1 + kt * 32, At + (tid + 256) * 8);
        glds16(gB0 + (size_t)kt * 24576, Bt + tid * 8);
        glds16(gB1 + (size_t)kt * 24576, Bt + (tid + 256) * 8);
        __syncthreads();
        s16x8 af[4], bf[4];
        #pragma unroll
        for (int i = 0; i < 4; ++i)
            af[i] = *(const s16x8*)(At + (wm * 64 + i * 16 + c) * 32 + q * 8);
        #pragma unroll
        for (int j = 0; j < 4; ++j)
            bf[j] = *(const s16x8*)(Bt + (wn * 64 + j * 16 + c) * 32 + q * 8);
        #pragma unroll
        for (int i = 0; i < 4; ++i)
            #pragma unroll
            for (int j = 0; j < 4; ++j)
                acc[i][j] = __builtin_amdgcn_mfma_f32_16x16x32_bf16(af[i], bf[j], acc[i][j], 0, 0, 0);
        __syncthreads();
    }
    #pragma unroll
    for (int i = 0; i < 4; ++i)
        #pragma unroll
        for (int j = 0; j < 4; ++j)
            #pragma unroll
            for (int jr = 0; jr < 4; ++jr) {
                int row = mb * 128 + wm * 64 + i * 16 + q * 4 + jr;
                int col = nb * 128 + wn * 64 + j * 16 + c;
                atomicAdd(&Orun[(size_t)row * DIM + col], acc[i][j][jr]);
            }
}

__global__ __launch_bounds__(256) void final_h(const float* __restrict__ Orun,
                                               const float* __restrict__ Lrow,
                                               u16* __restrict__ h) {
    int idx = blockIdx.x * 256 + threadIdx.x;
    if (idx >= M_ROWS * DIM) return;
    int r = idx / DIM;
    h[idx] = f2bf(Orun[idx] / Lrow[r]);
}

// ---------------- K3: out = h @ W_lin^T + b_lin (128-tile m97 style) --------
__global__ __launch_bounds__(256, 2) void final_gemm(const u16* __restrict__ h,
                                                     const u16* __restrict__ wlb,
                                                     const float* __restrict__ blin,
                                                     float* __restrict__ out) {
    __shared__ u16 At[4096];
    __shared__ u16 Bt[4096];
    int mb = blockIdx.x & 31, eb = blockIdx.x >> 5;
    int tid = threadIdx.x;
    int w = tid >> 6, lane = tid & 63, q = lane >> 4, c = lane & 15;
    int wm = w & 1, wn = w >> 1;
    int trow = tid >> 2, tch = tid & 3;
    const u16* gA0 = h + (size_t)(mb * 128 + trow) * DIM + tch * 8;
    const u16* gA1 = h + (size_t)(mb * 128 + 64 + trow) * DIM + tch * 8;
    const u16* gB0 = wlb + (size_t)(eb * 128 + trow) * DIM + tch * 8;
    const u16* gB1 = wlb + (size_t)(eb * 128 + 64 + trow) * DIM + tch * 8;
    f32x4 acc[4][4];
    #pragma unroll
    for (int i = 0; i < 4; ++i)
        #pragma unroll
        for (int j = 0; j < 4; ++j) acc[i][j] = (f32x4){0.f, 0.f, 0.f, 0.f};

    for (int ko = 0; ko < 24; ++ko) {
        glds16(gA0 + ko * 32, At + tid * 8);
        glds16(gA1 + ko * 32, At + (tid + 256) * 8);
        glds16(gB0 + ko * 32, Bt + tid * 8);
        glds16(gB1 + ko * 32, Bt + (tid + 256) * 8);
        __syncthreads();
        s16x8 af[4], bf[4];
        #pragma unroll
        for (int i = 0; i < 4; ++i)
            af[i] = *(const s16x8*)(At + (wm * 64 + i * 16 + c) * 32 + q * 8);
        #pragma unroll
        for (int j = 0; j < 4; ++j)
            bf[j] = *(const s16x8*)(Bt + (wn * 64 + j * 16 + c) * 32 + q * 8);
        #pragma unroll
        for (int i = 0; i < 4; ++i)
            #pragma unroll
            for (int j = 0; j < 4; ++j)
                acc[i][j] = __builtin_amdgcn_mfma_f32_16x16x32_bf16(af[i], bf[j], acc[i][j], 0, 0, 0);
        __syncthreads();
    }
    #pragma unroll
    for (int j = 0; j < 4; ++j) {
        int e = eb * 128 + wn * 64 + j * 16 + c;
        float bl = blin[e];
        #pragma unroll
        for (int i = 0; i < 4; ++i) {
            #pragma unroll
            for (int jr = 0; jr < 4; ++jr) {
                int row = mb * 128 + wm * 64 + i * 16 + q * 4 + jr;
                out[(size_t)row * DIM + e] = acc[i][j][jr] + bl;
            }
        }
    }
}

extern "C" void kernel_launch(void* const* d_in, const int* in_sizes, int n_in,
                              void* d_out, int out_size, void* d_ws, size_t ws_size,
                              hipStream_t stream) {
    const float* x  = (const float*)d_in[0];
    const float* Wv = (const float*)d_in[1];
    const float* bv = (const float*)d_in[2];
    const float* Wl = (const float*)d_in[3];
    const float* bl = (const float*)d_in[4];
    float* out = (float*)d_out;
    char* ws = (char*)d_ws;

    u16* xb    = (u16*)(ws + OFF_XB);
    u16* wlb   = (u16*)(ws + OFF_WLB);
    u16* wvb   = (u16*)(ws + OFF_WVB);
    u16* wvt32 = (u16*)(ws + OFF_WVT);
    u16* P     = (u16*)(ws + OFF_P);
    float* Orun  = (float*)(ws + OFF_ORUN);
    float* Lrow  = (float*)(ws + OFF_LROW);
    float* Brow  = (float*)(ws + OFF_BROW);
    unsigned* keys = (unsigned*)(ws + OFF_KEYS);
    u16* h       = (u16*)(ws + OFF_H);

    cast_bf16<<<(M_ROWS * DIM / 4 + 255) / 256, 256, 0, stream>>>(x, xb, M_ROWS * DIM / 4);
    cast_bf16<<<(DIM * DIM / 4 + 255) / 256, 256, 0, stream>>>(Wl, wlb, DIM * DIM / 4);
    {
        int ntask = VP2 * 96;
        prep_wvb<<<(ntask + 255) / 256, 256, 0, stream>>>(Wv, wvb, ntask);
    }
    init_keys<<<1, 1, 0, stream>>>(keys);
    hipMemsetAsync(Orun, 0, (size_t)M_ROWS * DIM * 4, stream);
    hipMemsetAsync(Lrow, 0, (size_t)M_ROWS * 4, stream);
    wnorm<<<VP2 / 32, 256, 0, stream>>>(wvb, keys);
    bmax_k<<<(VOCAB + 255) / 256, 256, 0, stream>>>(bv, keys);
    xnorm<<<M_ROWS / 4, 256, 0, stream>>>(x, keys, Brow);
    prep_wvt32<<<KT32, 256, 0, stream>>>(wvb, wvt32);

    // 5 chunks in 256-col tiles: 4x40 + 37 (197 tiles = 50432 cols)
    static const int chunk_start[5] = {0, 40, 80, 120, 160};
    static const int chunk_cnt[5]   = {40, 40, 40, 40, 37};
    for (int ci = 0; ci < 5; ++ci) {
        int cnt = chunk_cnt[ci];
        int v0 = chunk_start[ci] * 256;
        int CN = cnt * 256;
        int kt32 = CN / 32;
        int kts = (kt32 + 3) / 4;
        gemm1<<<16 * cnt, 512, 0, stream>>>(xb, wvb, bv, Brow, P, Lrow, v0, CN);
        gemm2<<<768, 256, 0, stream>>>(P, wvt32, Orun, CN, v0, kt32, kts);
    }
    final_h<<<(M_ROWS * DIM + 255) / 256, 256, 0, stream>>>(Orun, Lrow, h);
    final_gemm<<<192, 256, 0, stream>>>(h, wlb, bl, out);
}